// Round 2
// baseline (973.131 us; speedup 1.0000x reference)
//
#include <hip/hip_runtime.h>
#include <hip/hip_bf16.h>
#include <stdint.h>

#define BB 8
#define TT 168
#define NN 1024
#define BN_ 8192
#define FD_ 16
#define EE 16384

typedef short short8 __attribute__((ext_vector_type(8)));
typedef __bf16 bf16x8 __attribute__((ext_vector_type(8)));
typedef float f32x4 __attribute__((ext_vector_type(4)));

static __device__ __forceinline__ float b2f(ushort s) {
    unsigned u = ((unsigned)s) << 16;
    return __builtin_bit_cast(float, u);
}
static __device__ __forceinline__ ushort f2b(float f) {
    unsigned u = __builtin_bit_cast(unsigned, f);
    unsigned lsb = (u >> 16) & 1u;
    u += 0x7fffu + lsb;
    return (ushort)(u >> 16);
}
static __device__ __forceinline__ float sigf(float x) {
    return 1.f / (1.f + __expf(-x));
}
static __device__ __forceinline__ float tanhfast(float x) {
    float e = __expf(2.f * x);
    return 1.f - 2.f / (e + 1.f);
}
static __device__ __forceinline__ f32x4 mfma16(short8 a, short8 b, f32x4 c) {
    return __builtin_amdgcn_mfma_f32_16x16x32_bf16(
        __builtin_bit_cast(bf16x8, a), __builtin_bit_cast(bf16x8, b), c, 0, 0, 0);
}

// ---------------------------------------------------------------------------
// Cast the MFMA-path f32 operands to bf16 in ws. Layout (ushort offsets):
// [Wih 8192][Whh 65536][sta 262144][fcst 65536][sW 4096][fW 1024][uW 49152]
// [g0W 65536][g1W 65536]  -> total 586752
// ---------------------------------------------------------------------------
#define O_WIH 0
#define O_WHH 8192
#define O_STA 73728
#define O_FCS 335872
#define O_SW  401408
#define O_FW  405504
#define O_UW  406528
#define O_G0W 455680
#define O_G1W 521216
#define O_END 586752

__global__ void cast_kernel(const float* __restrict__ Wih, const float* __restrict__ Whh,
                            const float* __restrict__ sta, const float* __restrict__ fcst,
                            const float* __restrict__ sW, const float* __restrict__ fW,
                            const float* __restrict__ uW, const float* __restrict__ g0W,
                            const float* __restrict__ g1W, ushort* __restrict__ dst) {
    const int i = blockIdx.x * 256 + threadIdx.x;
    if (i >= O_END) return;
    float v;
    if      (i < O_WHH) v = Wih[i - O_WIH];
    else if (i < O_STA) v = Whh[i - O_WHH];
    else if (i < O_FCS) v = sta[i - O_STA];
    else if (i < O_SW)  v = fcst[i - O_FCS];
    else if (i < O_FW)  v = sW[i - O_SW];
    else if (i < O_UW)  v = fW[i - O_FW];
    else if (i < O_G0W) v = uW[i - O_UW];
    else if (i < O_G1W) v = g0W[i - O_G0W];
    else                v = g1W[i - O_G1W];
    dst[i] = f2b(v);
}

// ---------------------------------------------------------------------------
// LSTM: 16 nodes per block, 512 blocks. Whh|Wih (bf16) in registers (B-frags),
// [h|x] tile in LDS. 4 waves x 128 gate-cols each.
// ---------------------------------------------------------------------------
__global__ __launch_bounds__(256, 2) void lstm_kernel(
    const float* __restrict__ dyn,    // (B,T,N,16) f32
    const ushort* __restrict__ Wih,   // (512,16) bf16
    const ushort* __restrict__ Whh,   // (512,128) bf16
    const float* __restrict__ bih,    // (512,)
    const float* __restrict__ bhh,    // (512,)
    ushort* __restrict__ zsf)         // (8192,384) bf16, write cols 0..127
{
    constexpr int HS = 168;           // haug stride (128 h + 16 x + pad) -> 16B aligned
    __shared__ ushort haug[16 * HS];
    __shared__ float gates[16 * 516];

    const int tid = threadIdx.x;
    const int blk = blockIdx.x;
    const int b = blk >> 6;
    const int n0 = (blk & 63) << 4;
    const int w = tid >> 6, lane = tid & 63, quad = lane >> 4, m = lane & 15;

    // --- load B fragments: gate rows [w*128, w*128+128), K = [Whh(128) | Wih(16) | 0(16)]
    short8 Bf[5][8];
    const int gbase = w * 128;
#pragma unroll
    for (int ct = 0; ct < 8; ct++) {
        const int g = gbase + ct * 16 + m;
#pragma unroll
        for (int kt = 0; kt < 4; kt++)
            Bf[kt][ct] = *(const short8*)(Whh + g * 128 + kt * 32 + quad * 8);
        if (quad < 2) Bf[4][ct] = *(const short8*)(Wih + g * 16 + quad * 8);
        else          Bf[4][ct] = short8{0, 0, 0, 0, 0, 0, 0, 0};
    }

    // --- elementwise state: thread tid -> unit u = tid&127, nodes {tid>>7 + 2j}
    const int u = tid & 127;
    const int nb = tid >> 7;
    float c[8];
#pragma unroll
    for (int j = 0; j < 8; j++) c[j] = 0.f;
    const float bi  = bih[u] + bhh[u];
    const float bff = bih[128 + u] + bhh[128 + u];
    const float bg  = bih[256 + u] + bhh[256 + u];
    const float bo  = bih[384 + u] + bhh[384 + u];

    for (int i = tid; i < 16 * HS; i += 256) haug[i] = 0;
    __syncthreads();   // init must be visible before anyone writes x

    // --- x prefetch: thread -> (node tid>>4, feat tid&15)
    const int xn = tid >> 4, xf = tid & 15;
    const size_t xbase = (size_t)b * TT * NN * FD_ + (size_t)(n0 + xn) * FD_ + xf;
    float xv = dyn[xbase];  // t = 0

    for (int t = 0; t < TT; t++) {
        haug[xn * HS + 128 + xf] = f2b(xv);
        __syncthreads();
        if (t + 1 < TT) xv = dyn[xbase + (size_t)(t + 1) * NN * FD_];

        f32x4 acc[8];
#pragma unroll
        for (int ct = 0; ct < 8; ct++) acc[ct] = f32x4{0.f, 0.f, 0.f, 0.f};
#pragma unroll
        for (int kt = 0; kt < 5; kt++) {
            short8 a = *(const short8*)&haug[m * HS + kt * 32 + quad * 8];
#pragma unroll
            for (int ct = 0; ct < 8; ct++) acc[ct] = mfma16(a, Bf[kt][ct], acc[ct]);
        }
#pragma unroll
        for (int ct = 0; ct < 8; ct++) {
            const int col = gbase + ct * 16 + m;
#pragma unroll
            for (int r = 0; r < 4; r++)
                gates[(quad * 4 + r) * 516 + col] = acc[ct][r];
        }
        __syncthreads();

#pragma unroll
        for (int j = 0; j < 8; j++) {
            const int n = nb + 2 * j;
            const float* gr = &gates[n * 516];
            const float gi = gr[u] + bi;
            const float gf = gr[128 + u] + bff;
            const float gg = gr[256 + u] + bg;
            const float go = gr[384 + u] + bo;
            c[j] = sigf(gf) * c[j] + sigf(gi) * tanhfast(gg);
            const float h = sigf(go) * tanhfast(c[j]);
            haug[n * HS + u] = f2b(h);
            if (t == TT - 1) zsf[(size_t)(blk * 16 + n) * 384 + u] = f2b(h);
        }
    }
}

// ---------------------------------------------------------------------------
// Generic C = A @ Bt^T MFMA GEMM (M=8192 rows), bf16 operands, f32 bias.
// ---------------------------------------------------------------------------
__global__ __launch_bounds__(256) void gemm_kernel(
    const ushort* __restrict__ A, int lda,
    const ushort* __restrict__ Bt, int ldb,
    int Kact, int Ktiles, int Ncols,
    const float* __restrict__ bias, int relu,
    ushort* __restrict__ outb, int osb,
    float* __restrict__ outf, int osf)
{
    const int tid = threadIdx.x;
    const int lane = tid & 63, quad = lane >> 4, m = lane & 15;
    const int wave = blockIdx.x * 4 + (tid >> 6);
    const int ctiles = Ncols >> 4;
    const int r0 = (wave / ctiles) * 16;
    const int c0 = (wave % ctiles) * 16;

    f32x4 acc = f32x4{0.f, 0.f, 0.f, 0.f};
    for (int kt = 0; kt < Ktiles; kt++) {
        const int k = kt * 32 + quad * 8;
        short8 a, bf;
        if (k + 8 <= Kact) {
            a  = *(const short8*)(A  + (size_t)(r0 + m) * lda + k);
            bf = *(const short8*)(Bt + (size_t)(c0 + m) * ldb + k);
        } else {
#pragma unroll
            for (int j = 0; j < 8; j++) {
                a[j]  = (k + j < Kact) ? (short)A[(size_t)(r0 + m) * lda + k + j] : (short)0;
                bf[j] = (k + j < Kact) ? (short)Bt[(size_t)(c0 + m) * ldb + k + j] : (short)0;
            }
        }
        acc = mfma16(a, bf, acc);
    }
    const int col = c0 + m;
    const float bv = bias ? bias[col] : 0.f;
#pragma unroll
    for (int r = 0; r < 4; r++) {
        const int row = r0 + quad * 4 + r;
        float v = acc[r] + bv;
        if (relu) v = fmaxf(v, 0.f);
        outb[(size_t)row * osb + col] = f2b(v);
        if (outf) outf[(size_t)row * osf + col] = v;
    }
}

// ---------------------------------------------------------------------------
// Graph prep
// ---------------------------------------------------------------------------
__global__ void deg_kernel(const int* __restrict__ ei, const float* __restrict__ ew,
                           int* deg0, float* wsum) {
    const int e = blockIdx.x * 256 + threadIdx.x;
    if (e < EE) {
        const int d = ei[EE + e];
        atomicAdd(&deg0[d], 1);
        atomicAdd(&wsum[d], ew[e]);
    }
}

__global__ void scan_kernel(const int* __restrict__ deg0, const float* __restrict__ wsum,
                            int* offs, float* loopea) {
    __shared__ int sc[1024];
    const int t = threadIdx.x;
    const int d = deg0[t];
    sc[t] = d;
    __syncthreads();
    for (int o = 1; o < 1024; o <<= 1) {
        const int v = (t >= o) ? sc[t - o] : 0;
        __syncthreads();
        sc[t] += v;
        __syncthreads();
    }
    offs[t] = sc[t] - d;
    loopea[t] = wsum[t] / fmaxf((float)d, 1.f);
}

__global__ void fill_kernel(const int* __restrict__ ei, const int* __restrict__ offs,
                            int* cursor, int* eidx) {
    const int e = blockIdx.x * 256 + threadIdx.x;
    if (e < EE) {
        const int d = ei[EE + e];
        const int slot = atomicAdd(&cursor[d], 1);
        eidx[offs[d] + slot] = e;
    }
}

__global__ void sedge_kernel(const float* __restrict__ We0, const float* __restrict__ ae0,
                             const float* __restrict__ We1, const float* __restrict__ ae1,
                             float* se) {
    const int tid = threadIdx.x;
    const int lane = tid & 63, head = (tid >> 6) & 3, hop = tid >> 8;
    const float* W = hop ? We1 : We0;
    const float* A = hop ? ae1 : ae0;
    float s = W[head * 128 + lane] * A[head * 128 + lane] +
              W[head * 128 + 64 + lane] * A[head * 128 + 64 + lane];
#pragma unroll
    for (int o = 32; o; o >>= 1) s += __shfl_xor(s, o);
    if (lane == 0) se[hop * 4 + head] = s;
}

// ---------------------------------------------------------------------------
// Per-(node,head) attention scalars: as_, ad_
// ---------------------------------------------------------------------------
__global__ void att_kernel(const ushort* __restrict__ xl,
                           const float* __restrict__ asrc, const float* __restrict__ adst,
                           float* __restrict__ as_, float* __restrict__ ad_) {
    const int t = blockIdx.x * 256 + threadIdx.x;  // 32768
    const int n = t >> 2, h = t & 3;
    const ushort* row = xl + (size_t)n * 512 + h * 128;
    const float* s = asrc + h * 128;
    const float* d = adst + h * 128;
    float sa = 0.f, sd = 0.f;
#pragma unroll 8
    for (int k = 0; k < 128; k++) {
        const float x = b2f(row[k]);
        sa += x * s[k];
        sd += x * d[k];
    }
    as_[t] = sa;
    ad_[t] = sd;
}

// ---------------------------------------------------------------------------
// Fused GAT hop: one wave per (dst node, batch). Softmax (2-pass, no atomics),
// head-mean, bias, optional relu, residual, LayerNorm.
// ---------------------------------------------------------------------------
__global__ __launch_bounds__(256) void gat_kernel(
    float* __restrict__ hF, ushort* __restrict__ hB, const ushort* __restrict__ xl,
    const float* __restrict__ as_, const float* __restrict__ ad_,
    const int* __restrict__ eidx, const int* __restrict__ offs,
    const int* __restrict__ deg0, const float* __restrict__ loopea,
    const int* __restrict__ ei, const float* __restrict__ ew,
    const float* __restrict__ se4, const float* __restrict__ bias,
    const float* __restrict__ lng, const float* __restrict__ lnb, int relu)
{
    const int lane = threadIdx.x & 63;
    const int v = blockIdx.x * 4 + (threadIdx.x >> 6);
    const int b = v >> 10, n = v & 1023;
    const int dg = deg0[n], off = offs[n];

    float se[4], adv[4];
#pragma unroll
    for (int h = 0; h < 4; h++) { se[h] = se4[h]; adv[h] = ad_[v * 4 + h]; }

    // pass 1: denominators (+self loop)
    const float lea = loopea[n];
    float den[4], pself[4];
#pragma unroll
    for (int h = 0; h < 4; h++) {
        float a = as_[v * 4 + h] + adv[h] + lea * se[h];
        a = (a < 0.f) ? 0.2f * a : a;
        a = fminf(a, 60.f);
        pself[h] = __expf(a);
        den[h] = pself[h];
    }
    for (int i = 0; i < dg; i++) {
        const int e = eidx[off + i];
        const int src = b * 1024 + ei[e];
        const float eaw = ew[e];
#pragma unroll
        for (int h = 0; h < 4; h++) {
            float a = as_[src * 4 + h] + adv[h] + eaw * se[h];
            a = (a < 0.f) ? 0.2f * a : a;
            a = fminf(a, 60.f);
            den[h] += __expf(a);
        }
    }
    float inv[4];
#pragma unroll
    for (int h = 0; h < 4; h++) inv[h] = 1.f / den[h];

    // pass 2: weighted aggregation (mean over heads via 0.25 factor at end)
    float o0 = 0.f, o1 = 0.f;
#pragma unroll
    for (int h = 0; h < 4; h++) {
        const float wgt = pself[h] * inv[h];
        o0 += wgt * b2f(xl[(size_t)v * 512 + h * 128 + lane]);
        o1 += wgt * b2f(xl[(size_t)v * 512 + h * 128 + 64 + lane]);
    }
    for (int i = 0; i < dg; i++) {
        const int e = eidx[off + i];
        const int src = b * 1024 + ei[e];
        const float eaw = ew[e];
#pragma unroll
        for (int h = 0; h < 4; h++) {
            float a = as_[src * 4 + h] + adv[h] + eaw * se[h];
            a = (a < 0.f) ? 0.2f * a : a;
            a = fminf(a, 60.f);
            const float wgt = __expf(a) * inv[h];
            o0 += wgt * b2f(xl[(size_t)src * 512 + h * 128 + lane]);
            o1 += wgt * b2f(xl[(size_t)src * 512 + h * 128 + 64 + lane]);
        }
    }

    float d0 = o0 * 0.25f + bias[lane];
    float d1 = o1 * 0.25f + bias[64 + lane];
    if (relu) { d0 = fmaxf(d0, 0.f); d1 = fmaxf(d1, 0.f); }
    const float x0 = hF[(size_t)v * 128 + lane] + d0;
    const float x1 = hF[(size_t)v * 128 + 64 + lane] + d1;

    float s = x0 + x1;
#pragma unroll
    for (int o = 32; o; o >>= 1) s += __shfl_xor(s, o);
    const float mu = s * (1.f / 128.f);
    const float e0 = x0 - mu, e1 = x1 - mu;
    float vs = e0 * e0 + e1 * e1;
#pragma unroll
    for (int o = 32; o; o >>= 1) vs += __shfl_xor(vs, o);
    const float r = rsqrtf(vs * (1.f / 128.f) + 1e-5f);
    const float y0 = e0 * r * lng[lane] + lnb[lane];
    const float y1 = e1 * r * lng[64 + lane] + lnb[64 + lane];
    hF[(size_t)v * 128 + lane] = y0;
    hF[(size_t)v * 128 + 64 + lane] = y1;
    hB[(size_t)v * 128 + lane] = f2b(y0);
    hB[(size_t)v * 128 + 64 + lane] = f2b(y1);
}

// ---------------------------------------------------------------------------
// Output projection: one wave per node, f32 out
// ---------------------------------------------------------------------------
__global__ void out_kernel(const float* __restrict__ hF, const float* __restrict__ oW,
                           const float* __restrict__ ob, float* __restrict__ out) {
    const int lane = threadIdx.x & 63;
    const int v = blockIdx.x * 4 + (threadIdx.x >> 6);
    float s = hF[(size_t)v * 128 + lane] * oW[lane] +
              hF[(size_t)v * 128 + 64 + lane] * oW[64 + lane];
#pragma unroll
    for (int o = 32; o; o >>= 1) s += __shfl_xor(s, o);
    if (lane == 0) out[v] = s + ob[0];
}

// ---------------------------------------------------------------------------
extern "C" void kernel_launch(void* const* d_in, const int* in_sizes, int n_in,
                              void* d_out, int out_size, void* d_ws, size_t ws_size,
                              hipStream_t stream) {
    const float* dyn  = (const float*)d_in[0];
    const float* fcst = (const float*)d_in[1];
    const float* sta  = (const float*)d_in[2];
    const int*   ei   = (const int*)d_in[3];
    const float* ew   = (const float*)d_in[4];
    const float* lWih = (const float*)d_in[5];
    const float* lWhh = (const float*)d_in[6];
    const float* lbih = (const float*)d_in[7];
    const float* lbhh = (const float*)d_in[8];
    const float* sW = (const float*)d_in[9];
    const float* sb = (const float*)d_in[10];
    const float* fW = (const float*)d_in[11];
    const float* fb = (const float*)d_in[12];
    const float* uW = (const float*)d_in[13];
    const float* ub = (const float*)d_in[14];
    const float* g0W  = (const float*)d_in[15];
    const float* g0as = (const float*)d_in[16];
    const float* g0ad = (const float*)d_in[17];
    const float* g0ae = (const float*)d_in[18];
    const float* g0We = (const float*)d_in[19];
    const float* g0b  = (const float*)d_in[20];
    const float* g1W  = (const float*)d_in[21];
    const float* g1as = (const float*)d_in[22];
    const float* g1ad = (const float*)d_in[23];
    const float* g1ae = (const float*)d_in[24];
    const float* g1We = (const float*)d_in[25];
    const float* g1b  = (const float*)d_in[26];
    const float* ln0g = (const float*)d_in[27];
    const float* ln0b = (const float*)d_in[28];
    const float* ln1g = (const float*)d_in[29];
    const float* ln1b = (const float*)d_in[30];
    const float* oW = (const float*)d_in[31];
    const float* ob = (const float*)d_in[32];

    char* p = (char*)d_ws;
    ushort* castB = (ushort*)p; p += (size_t)O_END * 2 + 512;   // bf16 weights/statics
    ushort* zsf = (ushort*)p;  p += (size_t)BN_ * 384 * 2;
    float*  hF  = (float*)p;   p += (size_t)BN_ * 128 * 4;
    ushort* hB  = (ushort*)p;  p += (size_t)BN_ * 128 * 2;
    ushort* xl  = (ushort*)p;  p += (size_t)BN_ * 512 * 2;
    float*  asb = (float*)p;   p += (size_t)BN_ * 4 * 4;
    float*  adb = (float*)p;   p += (size_t)BN_ * 4 * 4;
    int*    deg0   = (int*)p;   p += 4096;
    float*  wsum   = (float*)p; p += 4096;
    int*    offs   = (int*)p;   p += 4096;
    int*    cursor = (int*)p;   p += 4096;
    float*  loopea = (float*)p; p += 4096;
    int*    eidx   = (int*)p;   p += (size_t)EE * 4;
    float*  se     = (float*)p; p += 256;

    const ushort* WihB = castB + O_WIH;
    const ushort* WhhB = castB + O_WHH;
    const ushort* staB = castB + O_STA;
    const ushort* fcsB = castB + O_FCS;
    const ushort* sWB  = castB + O_SW;
    const ushort* fWB  = castB + O_FW;
    const ushort* uWB  = castB + O_UW;
    const ushort* g0WB = castB + O_G0W;
    const ushort* g1WB = castB + O_G1W;

    hipMemsetAsync(deg0, 0, 4096, stream);
    hipMemsetAsync(wsum, 0, 4096, stream);
    hipMemsetAsync(cursor, 0, 4096, stream);

    cast_kernel<<<(O_END + 255) / 256, 256, 0, stream>>>(lWih, lWhh, sta, fcst, sW, fW,
                                                         uW, g0W, g1W, castB);
    deg_kernel<<<EE / 256, 256, 0, stream>>>(ei, ew, deg0, wsum);
    scan_kernel<<<1, 1024, 0, stream>>>(deg0, wsum, offs, loopea);
    fill_kernel<<<EE / 256, 256, 0, stream>>>(ei, offs, cursor, eidx);
    sedge_kernel<<<1, 512, 0, stream>>>(g0We, g0ae, g1We, g1ae, se);

    lstm_kernel<<<512, 256, 0, stream>>>(dyn, WihB, WhhB, lbih, lbhh, zsf);

    // s = relu(sta @ sW^T + sb) -> zsf cols 128..255
    gemm_kernel<<<1024, 256, 0, stream>>>(staB, 32, sWB, 32, 32, 1, 128, sb, 1,
                                          zsf + 128, 384, nullptr, 0);
    // f = relu(fcst @ fW^T + fb) -> zsf cols 256..383
    gemm_kernel<<<1024, 256, 0, stream>>>(fcsB, 8, fWB, 8, 8, 1, 128, fb, 1,
                                          zsf + 256, 384, nullptr, 0);
    // h = relu(zsf @ uW^T + ub) -> hB + hF
    gemm_kernel<<<1024, 256, 0, stream>>>(zsf, 384, uWB, 384, 384, 12, 128, ub, 1,
                                          hB, 128, hF, 128);

    // hop 0
    gemm_kernel<<<4096, 256, 0, stream>>>(hB, 128, g0WB, 128, 128, 4, 512, nullptr, 0,
                                          xl, 512, nullptr, 0);
    att_kernel<<<128, 256, 0, stream>>>(xl, g0as, g0ad, asb, adb);
    gat_kernel<<<2048, 256, 0, stream>>>(hF, hB, xl, asb, adb, eidx, offs, deg0, loopea,
                                         ei, ew, se, g0b, ln0g, ln0b, 1);
    // hop 1
    gemm_kernel<<<4096, 256, 0, stream>>>(hB, 128, g1WB, 128, 128, 4, 512, nullptr, 0,
                                          xl, 512, nullptr, 0);
    att_kernel<<<128, 256, 0, stream>>>(xl, g1as, g1ad, asb, adb);
    gat_kernel<<<2048, 256, 0, stream>>>(hF, hB, xl, asb, adb, eidx, offs, deg0, loopea,
                                         ei, ew, se + 4, g1b, ln1g, ln1b, 0);

    out_kernel<<<2048, 256, 0, stream>>>(hF, oW, ob, (float*)d_out);
}

// Round 3
// 632.943 us; speedup vs baseline: 1.5375x; 1.5375x over previous
//
#include <hip/hip_runtime.h>
#include <hip/hip_bf16.h>
#include <stdint.h>

#define BB 8
#define TT 168
#define NN 1024
#define BN_ 8192
#define FD_ 16
#define EE 16384

typedef short short8 __attribute__((ext_vector_type(8)));
typedef __bf16 bf16x8 __attribute__((ext_vector_type(8)));
typedef float f32x4 __attribute__((ext_vector_type(4)));

#if __has_builtin(__builtin_amdgcn_exp2f)
#define EXP2(x) __builtin_amdgcn_exp2f(x)
#else
#define EXP2(x) exp2f(x)
#endif
#if __has_builtin(__builtin_amdgcn_rcpf)
#define RCPF(x) __builtin_amdgcn_rcpf(x)
#else
#define RCPF(x) (1.f / (x))
#endif
#define L2E 1.4426950408889634f
#define T2E 2.8853900817779268f

static __device__ __forceinline__ float b2f(ushort s) {
    unsigned u = ((unsigned)s) << 16;
    return __builtin_bit_cast(float, u);
}
static __device__ __forceinline__ ushort f2b(float f) {
    unsigned u = __builtin_bit_cast(unsigned, f);
    unsigned lsb = (u >> 16) & 1u;
    u += 0x7fffu + lsb;
    return (ushort)(u >> 16);
}
static __device__ __forceinline__ float sigf(float x) {
    return 1.f / (1.f + __expf(-x));
}
static __device__ __forceinline__ f32x4 mfma16(short8 a, short8 b, f32x4 c) {
    return __builtin_amdgcn_mfma_f32_16x16x32_bf16(
        __builtin_bit_cast(bf16x8, a), __builtin_bit_cast(bf16x8, b), c, 0, 0, 0);
}

// ---------------------------------------------------------------------------
// Cast the MFMA-path f32 operands to bf16 in ws.
// ---------------------------------------------------------------------------
#define O_WIH 0
#define O_WHH 8192
#define O_STA 73728
#define O_FCS 335872
#define O_SW  401408
#define O_FW  405504
#define O_UW  406528
#define O_G0W 455680
#define O_G1W 521216
#define O_END 586752

__global__ void cast_kernel(const float* __restrict__ Wih, const float* __restrict__ Whh,
                            const float* __restrict__ sta, const float* __restrict__ fcst,
                            const float* __restrict__ sW, const float* __restrict__ fW,
                            const float* __restrict__ uW, const float* __restrict__ g0W,
                            const float* __restrict__ g1W, ushort* __restrict__ dst) {
    const int i = blockIdx.x * 256 + threadIdx.x;
    if (i >= O_END) return;
    float v;
    if      (i < O_WHH) v = Wih[i - O_WIH];
    else if (i < O_STA) v = Whh[i - O_WHH];
    else if (i < O_FCS) v = sta[i - O_STA];
    else if (i < O_SW)  v = fcst[i - O_FCS];
    else if (i < O_FW)  v = sW[i - O_SW];
    else if (i < O_UW)  v = fW[i - O_FW];
    else if (i < O_G0W) v = uW[i - O_UW];
    else if (i < O_G1W) v = g0W[i - O_G0W];
    else                v = g1W[i - O_G1W];
    dst[i] = f2b(v);
}

// ---------------------------------------------------------------------------
// LSTM: 16 nodes/block, 512 blocks, 4 waves. Wave w owns col-tiles
// {g*8 + 2w + jj} so each LANE holds all 4 gates of its (node,unit) pairs
// in-register -> elementwise phase has no LDS round-trip.
// ---------------------------------------------------------------------------
__global__ __launch_bounds__(256, 2) void lstm_kernel(
    const float* __restrict__ dyn,    // (B,T,N,16) f32
    const ushort* __restrict__ Wih,   // (512,16) bf16
    const ushort* __restrict__ Whh,   // (512,128) bf16
    const float* __restrict__ bih,    // (512,)
    const float* __restrict__ bhh,    // (512,)
    ushort* __restrict__ zsf)         // (8192,384) bf16, cols 0..127
{
    constexpr int HS = 168;           // [h(128) | x(16) | zero-pad(24)]
    __shared__ ushort haug[16 * HS];

    const int tid = threadIdx.x;
    const int blk = blockIdx.x;
    const int b = blk >> 6;
    const int n0 = (blk & 63) << 4;
    const int w = tid >> 6, lane = tid & 63, quad = lane >> 4, m = lane & 15;

    // B fragments + folded exp2 bias constants per (gate, jj)
    short8 Bf[5][4][2];
    float ci[2], cf[2], cg[2], co[2];
#pragma unroll
    for (int jj = 0; jj < 2; jj++) {
        const int u = (2 * w + jj) * 16 + m;
#pragma unroll
        for (int g = 0; g < 4; g++) {
            const int grow = g * 128 + u;
#pragma unroll
            for (int kt = 0; kt < 4; kt++)
                Bf[kt][g][jj] = *(const short8*)(Whh + grow * 128 + kt * 32 + quad * 8);
            if (quad < 2) Bf[4][g][jj] = *(const short8*)(Wih + grow * 16 + quad * 8);
            else          Bf[4][g][jj] = short8{0, 0, 0, 0, 0, 0, 0, 0};
        }
        ci[jj] = -L2E * (bih[u] + bhh[u]);
        cf[jj] = -L2E * (bih[128 + u] + bhh[128 + u]);
        cg[jj] =  T2E * (bih[256 + u] + bhh[256 + u]);
        co[jj] = -L2E * (bih[384 + u] + bhh[384 + u]);
    }

    float c[2][4];
#pragma unroll
    for (int jj = 0; jj < 2; jj++)
#pragma unroll
        for (int r = 0; r < 4; r++) c[jj][r] = 0.f;

    for (int i = tid; i < 16 * HS; i += 256) haug[i] = 0;
    __syncthreads();

    // x staging: thread -> (node tid>>4, feat tid&15)
    const int xn = tid >> 4, xf = tid & 15;
    const size_t xbase = (size_t)b * TT * NN * FD_ + (size_t)(n0 + xn) * FD_ + xf;
    float xv = dyn[xbase];  // t = 0

    for (int t = 0; t < TT; t++) {
        haug[xn * HS + 128 + xf] = f2b(xv);
        __syncthreads();
        if (t + 1 < TT) xv = dyn[xbase + (size_t)(t + 1) * NN * FD_];

        f32x4 acc[4][2];
#pragma unroll
        for (int g = 0; g < 4; g++)
#pragma unroll
            for (int jj = 0; jj < 2; jj++) acc[g][jj] = f32x4{0.f, 0.f, 0.f, 0.f};
#pragma unroll
        for (int kt = 0; kt < 5; kt++) {
            short8 a = *(const short8*)&haug[m * HS + kt * 32 + quad * 8];
#pragma unroll
            for (int g = 0; g < 4; g++)
#pragma unroll
                for (int jj = 0; jj < 2; jj++)
                    acc[g][jj] = mfma16(a, Bf[kt][g][jj], acc[g][jj]);
        }
        __syncthreads();   // all haug reads done before h(t) writes

#pragma unroll
        for (int jj = 0; jj < 2; jj++) {
            const int u = (2 * w + jj) * 16 + m;
#pragma unroll
            for (int r = 0; r < 4; r++) {
                const int n = quad * 4 + r;
                const float si = RCPF(1.f + EXP2(fmaf(acc[0][jj][r], -L2E, ci[jj])));
                const float sf = RCPF(1.f + EXP2(fmaf(acc[1][jj][r], -L2E, cf[jj])));
                const float tg = 1.f - 2.f * RCPF(1.f + EXP2(fmaf(acc[2][jj][r], T2E, cg[jj])));
                const float so = RCPF(1.f + EXP2(fmaf(acc[3][jj][r], -L2E, co[jj])));
                const float cc = fmaf(sf, c[jj][r], si * tg);
                c[jj][r] = cc;
                const float tc = 1.f - 2.f * RCPF(1.f + EXP2(T2E * cc));
                const float h = so * tc;
                haug[n * HS + u] = f2b(h);
                if (t == TT - 1) zsf[(size_t)(blk * 16 + n) * 384 + u] = f2b(h);
            }
        }
    }
}

// ---------------------------------------------------------------------------
// Generic C = A @ Bt^T MFMA GEMM (M=8192 rows), bf16 operands, f32 bias.
// ---------------------------------------------------------------------------
__global__ __launch_bounds__(256) void gemm_kernel(
    const ushort* __restrict__ A, int lda,
    const ushort* __restrict__ Bt, int ldb,
    int Kact, int Ktiles, int Ncols,
    const float* __restrict__ bias, int relu,
    ushort* __restrict__ outb, int osb,
    float* __restrict__ outf, int osf)
{
    const int tid = threadIdx.x;
    const int lane = tid & 63, quad = lane >> 4, m = lane & 15;
    const int wave = blockIdx.x * 4 + (tid >> 6);
    const int ctiles = Ncols >> 4;
    const int r0 = (wave / ctiles) * 16;
    const int c0 = (wave % ctiles) * 16;

    f32x4 acc = f32x4{0.f, 0.f, 0.f, 0.f};
    for (int kt = 0; kt < Ktiles; kt++) {
        const int k = kt * 32 + quad * 8;
        short8 a, bf;
        if (k + 8 <= Kact) {
            a  = *(const short8*)(A  + (size_t)(r0 + m) * lda + k);
            bf = *(const short8*)(Bt + (size_t)(c0 + m) * ldb + k);
        } else {
#pragma unroll
            for (int j = 0; j < 8; j++) {
                a[j]  = (k + j < Kact) ? (short)A[(size_t)(r0 + m) * lda + k + j] : (short)0;
                bf[j] = (k + j < Kact) ? (short)Bt[(size_t)(c0 + m) * ldb + k + j] : (short)0;
            }
        }
        acc = mfma16(a, bf, acc);
    }
    const int col = c0 + m;
    const float bv = bias ? bias[col] : 0.f;
#pragma unroll
    for (int r = 0; r < 4; r++) {
        const int row = r0 + quad * 4 + r;
        float v = acc[r] + bv;
        if (relu) v = fmaxf(v, 0.f);
        outb[(size_t)row * osb + col] = f2b(v);
        if (outf) outf[(size_t)row * osf + col] = v;
    }
}

// ---------------------------------------------------------------------------
// Graph prep
// ---------------------------------------------------------------------------
__global__ void deg_kernel(const int* __restrict__ ei, const float* __restrict__ ew,
                           int* deg0, float* wsum) {
    const int e = blockIdx.x * 256 + threadIdx.x;
    if (e < EE) {
        const int d = ei[EE + e];
        atomicAdd(&deg0[d], 1);
        atomicAdd(&wsum[d], ew[e]);
    }
}

__global__ void scan_kernel(const int* __restrict__ deg0, const float* __restrict__ wsum,
                            int* offs, float* loopea) {
    __shared__ int sc[1024];
    const int t = threadIdx.x;
    const int d = deg0[t];
    sc[t] = d;
    __syncthreads();
    for (int o = 1; o < 1024; o <<= 1) {
        const int v = (t >= o) ? sc[t - o] : 0;
        __syncthreads();
        sc[t] += v;
        __syncthreads();
    }
    offs[t] = sc[t] - d;
    loopea[t] = wsum[t] / fmaxf((float)d, 1.f);
}

__global__ void fill_kernel(const int* __restrict__ ei, const int* __restrict__ offs,
                            int* cursor, int* eidx) {
    const int e = blockIdx.x * 256 + threadIdx.x;
    if (e < EE) {
        const int d = ei[EE + e];
        const int slot = atomicAdd(&cursor[d], 1);
        eidx[offs[d] + slot] = e;
    }
}

__global__ void sedge_kernel(const float* __restrict__ We0, const float* __restrict__ ae0,
                             const float* __restrict__ We1, const float* __restrict__ ae1,
                             float* se) {
    const int tid = threadIdx.x;
    const int lane = tid & 63, head = (tid >> 6) & 3, hop = tid >> 8;
    const float* W = hop ? We1 : We0;
    const float* A = hop ? ae1 : ae0;
    float s = W[head * 128 + lane] * A[head * 128 + lane] +
              W[head * 128 + 64 + lane] * A[head * 128 + 64 + lane];
#pragma unroll
    for (int o = 32; o; o >>= 1) s += __shfl_xor(s, o);
    if (lane == 0) se[hop * 4 + head] = s;
}

// ---------------------------------------------------------------------------
// Per-(node,head) attention scalars. Wave handles 4 nodes (16 rows);
// 4 lanes per row, short8 loads, shuffle-reduce.
// ---------------------------------------------------------------------------
__global__ __launch_bounds__(256) void att_kernel(
    const ushort* __restrict__ xl, const float* __restrict__ asrc,
    const float* __restrict__ adst, float* __restrict__ as_, float* __restrict__ ad_) {
    const int lane = threadIdx.x & 63;
    const int wid = blockIdx.x * 4 + (threadIdx.x >> 6);  // 0..2047
    const int base = wid * 4;
    const int p = lane >> 2;            // 0..15
    const int dn = p >> 2, h = p & 3;
    const int sub = lane & 3;
    const ushort* row = xl + (size_t)(base + dn) * 512 + h * 128 + sub * 32;
    const float* sv = asrc + h * 128 + sub * 32;
    const float* dv = adst + h * 128 + sub * 32;
    float sa = 0.f, sd = 0.f;
#pragma unroll
    for (int j = 0; j < 4; j++) {
        short8 x8 = *(const short8*)(row + j * 8);
#pragma unroll
        for (int k = 0; k < 8; k++) {
            const float x = b2f((ushort)x8[k]);
            sa = fmaf(x, sv[j * 8 + k], sa);
            sd = fmaf(x, dv[j * 8 + k], sd);
        }
    }
    sa += __shfl_xor(sa, 1); sa += __shfl_xor(sa, 2);
    sd += __shfl_xor(sd, 1); sd += __shfl_xor(sd, 2);
    if (sub == 0) {
        as_[(base + dn) * 4 + h] = sa;
        ad_[(base + dn) * 4 + h] = sd;
    }
}

// ---------------------------------------------------------------------------
// Fused GAT hop: one wave per (dst node, batch). Softmax (2-pass, no atomics),
// head-mean, bias, optional relu, residual, LayerNorm.
// ---------------------------------------------------------------------------
__global__ __launch_bounds__(256) void gat_kernel(
    float* __restrict__ hF, ushort* __restrict__ hB, const ushort* __restrict__ xl,
    const float* __restrict__ as_, const float* __restrict__ ad_,
    const int* __restrict__ eidx, const int* __restrict__ offs,
    const int* __restrict__ deg0, const float* __restrict__ loopea,
    const int* __restrict__ ei, const float* __restrict__ ew,
    const float* __restrict__ se4, const float* __restrict__ bias,
    const float* __restrict__ lng, const float* __restrict__ lnb, int relu)
{
    const int lane = threadIdx.x & 63;
    const int v = blockIdx.x * 4 + (threadIdx.x >> 6);
    const int b = v >> 10, n = v & 1023;
    const int dg = deg0[n], off = offs[n];

    float se[4], adv[4];
#pragma unroll
    for (int h = 0; h < 4; h++) { se[h] = se4[h]; adv[h] = ad_[v * 4 + h]; }

    // pass 1: denominators (+self loop)
    const float lea = loopea[n];
    float den[4], pself[4];
#pragma unroll
    for (int h = 0; h < 4; h++) {
        float a = as_[v * 4 + h] + adv[h] + lea * se[h];
        a = (a < 0.f) ? 0.2f * a : a;
        a = fminf(a, 60.f);
        pself[h] = __expf(a);
        den[h] = pself[h];
    }
    for (int i = 0; i < dg; i++) {
        const int e = eidx[off + i];
        const int src = b * 1024 + ei[e];
        const float eaw = ew[e];
#pragma unroll
        for (int h = 0; h < 4; h++) {
            float a = as_[src * 4 + h] + adv[h] + eaw * se[h];
            a = (a < 0.f) ? 0.2f * a : a;
            a = fminf(a, 60.f);
            den[h] += __expf(a);
        }
    }
    float inv[4];
#pragma unroll
    for (int h = 0; h < 4; h++) inv[h] = 1.f / den[h];

    // pass 2: weighted aggregation (mean over heads via 0.25 factor at end)
    float o0 = 0.f, o1 = 0.f;
#pragma unroll
    for (int h = 0; h < 4; h++) {
        const float wgt = pself[h] * inv[h];
        o0 += wgt * b2f(xl[(size_t)v * 512 + h * 128 + lane]);
        o1 += wgt * b2f(xl[(size_t)v * 512 + h * 128 + 64 + lane]);
    }
    for (int i = 0; i < dg; i++) {
        const int e = eidx[off + i];
        const int src = b * 1024 + ei[e];
        const float eaw = ew[e];
#pragma unroll
        for (int h = 0; h < 4; h++) {
            float a = as_[src * 4 + h] + adv[h] + eaw * se[h];
            a = (a < 0.f) ? 0.2f * a : a;
            a = fminf(a, 60.f);
            const float wgt = __expf(a) * inv[h];
            o0 += wgt * b2f(xl[(size_t)src * 512 + h * 128 + lane]);
            o1 += wgt * b2f(xl[(size_t)src * 512 + h * 128 + 64 + lane]);
        }
    }

    float d0 = o0 * 0.25f + bias[lane];
    float d1 = o1 * 0.25f + bias[64 + lane];
    if (relu) { d0 = fmaxf(d0, 0.f); d1 = fmaxf(d1, 0.f); }
    const float x0 = hF[(size_t)v * 128 + lane] + d0;
    const float x1 = hF[(size_t)v * 128 + 64 + lane] + d1;

    float s = x0 + x1;
#pragma unroll
    for (int o = 32; o; o >>= 1) s += __shfl_xor(s, o);
    const float mu = s * (1.f / 128.f);
    const float e0 = x0 - mu, e1 = x1 - mu;
    float vs = e0 * e0 + e1 * e1;
#pragma unroll
    for (int o = 32; o; o >>= 1) vs += __shfl_xor(vs, o);
    const float r = rsqrtf(vs * (1.f / 128.f) + 1e-5f);
    const float y0 = e0 * r * lng[lane] + lnb[lane];
    const float y1 = e1 * r * lng[64 + lane] + lnb[64 + lane];
    hF[(size_t)v * 128 + lane] = y0;
    hF[(size_t)v * 128 + 64 + lane] = y1;
    hB[(size_t)v * 128 + lane] = f2b(y0);
    hB[(size_t)v * 128 + 64 + lane] = f2b(y1);
}

// ---------------------------------------------------------------------------
// Output projection: one wave per node, f32 out
// ---------------------------------------------------------------------------
__global__ void out_kernel(const float* __restrict__ hF, const float* __restrict__ oW,
                           const float* __restrict__ ob, float* __restrict__ out) {
    const int lane = threadIdx.x & 63;
    const int v = blockIdx.x * 4 + (threadIdx.x >> 6);
    float s = hF[(size_t)v * 128 + lane] * oW[lane] +
              hF[(size_t)v * 128 + 64 + lane] * oW[64 + lane];
#pragma unroll
    for (int o = 32; o; o >>= 1) s += __shfl_xor(s, o);
    if (lane == 0) out[v] = s + ob[0];
}

// ---------------------------------------------------------------------------
extern "C" void kernel_launch(void* const* d_in, const int* in_sizes, int n_in,
                              void* d_out, int out_size, void* d_ws, size_t ws_size,
                              hipStream_t stream) {
    const float* dyn  = (const float*)d_in[0];
    const float* fcst = (const float*)d_in[1];
    const float* sta  = (const float*)d_in[2];
    const int*   ei   = (const int*)d_in[3];
    const float* ew   = (const float*)d_in[4];
    const float* lWih = (const float*)d_in[5];
    const float* lWhh = (const float*)d_in[6];
    const float* lbih = (const float*)d_in[7];
    const float* lbhh = (const float*)d_in[8];
    const float* sW = (const float*)d_in[9];
    const float* sb = (const float*)d_in[10];
    const float* fW = (const float*)d_in[11];
    const float* fb = (const float*)d_in[12];
    const float* uW = (const float*)d_in[13];
    const float* ub = (const float*)d_in[14];
    const float* g0W  = (const float*)d_in[15];
    const float* g0as = (const float*)d_in[16];
    const float* g0ad = (const float*)d_in[17];
    const float* g0ae = (const float*)d_in[18];
    const float* g0We = (const float*)d_in[19];
    const float* g0b  = (const float*)d_in[20];
    const float* g1W  = (const float*)d_in[21];
    const float* g1as = (const float*)d_in[22];
    const float* g1ad = (const float*)d_in[23];
    const float* g1ae = (const float*)d_in[24];
    const float* g1We = (const float*)d_in[25];
    const float* g1b  = (const float*)d_in[26];
    const float* ln0g = (const float*)d_in[27];
    const float* ln0b = (const float*)d_in[28];
    const float* ln1g = (const float*)d_in[29];
    const float* ln1b = (const float*)d_in[30];
    const float* oW = (const float*)d_in[31];
    const float* ob = (const float*)d_in[32];

    char* p = (char*)d_ws;
    ushort* castB = (ushort*)p; p += (size_t)O_END * 2 + 512;
    ushort* zsf = (ushort*)p;  p += (size_t)BN_ * 384 * 2;
    float*  hF  = (float*)p;   p += (size_t)BN_ * 128 * 4;
    ushort* hB  = (ushort*)p;  p += (size_t)BN_ * 128 * 2;
    ushort* xl  = (ushort*)p;  p += (size_t)BN_ * 512 * 2;
    float*  asb = (float*)p;   p += (size_t)BN_ * 4 * 4;
    float*  adb = (float*)p;   p += (size_t)BN_ * 4 * 4;
    int*    deg0   = (int*)p;   p += 4096;
    float*  wsum   = (float*)p; p += 4096;
    int*    offs   = (int*)p;   p += 4096;
    int*    cursor = (int*)p;   p += 4096;
    float*  loopea = (float*)p; p += 4096;
    int*    eidx   = (int*)p;   p += (size_t)EE * 4;
    float*  se     = (float*)p; p += 256;

    const ushort* WihB = castB + O_WIH;
    const ushort* WhhB = castB + O_WHH;
    const ushort* staB = castB + O_STA;
    const ushort* fcsB = castB + O_FCS;
    const ushort* sWB  = castB + O_SW;
    const ushort* fWB  = castB + O_FW;
    const ushort* uWB  = castB + O_UW;
    const ushort* g0WB = castB + O_G0W;
    const ushort* g1WB = castB + O_G1W;

    hipMemsetAsync(deg0, 0, 4096, stream);
    hipMemsetAsync(wsum, 0, 4096, stream);
    hipMemsetAsync(cursor, 0, 4096, stream);

    cast_kernel<<<(O_END + 255) / 256, 256, 0, stream>>>(lWih, lWhh, sta, fcst, sW, fW,
                                                         uW, g0W, g1W, castB);
    deg_kernel<<<EE / 256, 256, 0, stream>>>(ei, ew, deg0, wsum);
    scan_kernel<<<1, 1024, 0, stream>>>(deg0, wsum, offs, loopea);
    fill_kernel<<<EE / 256, 256, 0, stream>>>(ei, offs, cursor, eidx);
    sedge_kernel<<<1, 512, 0, stream>>>(g0We, g0ae, g1We, g1ae, se);

    lstm_kernel<<<512, 256, 0, stream>>>(dyn, WihB, WhhB, lbih, lbhh, zsf);

    gemm_kernel<<<1024, 256, 0, stream>>>(staB, 32, sWB, 32, 32, 1, 128, sb, 1,
                                          zsf + 128, 384, nullptr, 0);
    gemm_kernel<<<1024, 256, 0, stream>>>(fcsB, 8, fWB, 8, 8, 1, 128, fb, 1,
                                          zsf + 256, 384, nullptr, 0);
    gemm_kernel<<<1024, 256, 0, stream>>>(zsf, 384, uWB, 384, 384, 12, 128, ub, 1,
                                          hB, 128, hF, 128);

    // hop 0
    gemm_kernel<<<4096, 256, 0, stream>>>(hB, 128, g0WB, 128, 128, 4, 512, nullptr, 0,
                                          xl, 512, nullptr, 0);
    att_kernel<<<512, 256, 0, stream>>>(xl, g0as, g0ad, asb, adb);
    gat_kernel<<<2048, 256, 0, stream>>>(hF, hB, xl, asb, adb, eidx, offs, deg0, loopea,
                                         ei, ew, se, g0b, ln0g, ln0b, 1);
    // hop 1
    gemm_kernel<<<4096, 256, 0, stream>>>(hB, 128, g1WB, 128, 128, 4, 512, nullptr, 0,
                                          xl, 512, nullptr, 0);
    att_kernel<<<512, 256, 0, stream>>>(xl, g1as, g1ad, asb, adb);
    gat_kernel<<<2048, 256, 0, stream>>>(hF, hB, xl, asb, adb, eidx, offs, deg0, loopea,
                                         ei, ew, se + 4, g1b, ln1g, ln1b, 0);

    out_kernel<<<2048, 256, 0, stream>>>(hF, oW, ob, (float*)d_out);
}

// Round 4
// 580.248 us; speedup vs baseline: 1.6771x; 1.0908x over previous
//
#include <hip/hip_runtime.h>
#include <hip/hip_bf16.h>
#include <stdint.h>

#define BB 8
#define TT 168
#define NN 1024
#define BN_ 8192
#define FD_ 16
#define EE 16384

typedef short short8 __attribute__((ext_vector_type(8)));
typedef __bf16 bf16x8 __attribute__((ext_vector_type(8)));
typedef float f32x4 __attribute__((ext_vector_type(4)));

#if __has_builtin(__builtin_amdgcn_exp2f)
#define EXP2(x) __builtin_amdgcn_exp2f(x)
#else
#define EXP2(x) exp2f(x)
#endif
#if __has_builtin(__builtin_amdgcn_rcpf)
#define RCPF(x) __builtin_amdgcn_rcpf(x)
#else
#define RCPF(x) (1.f / (x))
#endif
#define L2E 1.4426950408889634f
#define T2E 2.8853900817779268f

static __device__ __forceinline__ float b2f(ushort s) {
    unsigned u = ((unsigned)s) << 16;
    return __builtin_bit_cast(float, u);
}
static __device__ __forceinline__ ushort f2b(float f) {      // RNE
    unsigned u = __builtin_bit_cast(unsigned, f);
    unsigned lsb = (u >> 16) & 1u;
    u += 0x7fffu + lsb;
    return (ushort)(u >> 16);
}
static __device__ __forceinline__ ushort f2b_fast(float f) { // round-half-up, 2 ops
    unsigned u = __builtin_bit_cast(unsigned, f);
    return (ushort)((u + 0x8000u) >> 16);
}
static __device__ __forceinline__ f32x4 mfma16(short8 a, short8 b, f32x4 c) {
    return __builtin_amdgcn_mfma_f32_16x16x32_bf16(
        __builtin_bit_cast(bf16x8, a), __builtin_bit_cast(bf16x8, b), c, 0, 0, 0);
}

// ---------------------------------------------------------------------------
// Cast the MFMA-path f32 operands to bf16 in ws.
// ---------------------------------------------------------------------------
#define O_WIH 0
#define O_WHH 8192
#define O_STA 73728
#define O_FCS 335872
#define O_SW  401408
#define O_FW  405504
#define O_UW  406528
#define O_G0W 455680
#define O_G1W 521216
#define O_END 586752

__global__ void cast_kernel(const float* __restrict__ Wih, const float* __restrict__ Whh,
                            const float* __restrict__ sta, const float* __restrict__ fcst,
                            const float* __restrict__ sW, const float* __restrict__ fW,
                            const float* __restrict__ uW, const float* __restrict__ g0W,
                            const float* __restrict__ g1W, ushort* __restrict__ dst) {
    const int i = blockIdx.x * 256 + threadIdx.x;
    if (i >= O_END) return;
    float v;
    if      (i < O_WHH) v = Wih[i - O_WIH];
    else if (i < O_STA) v = Whh[i - O_WHH];
    else if (i < O_FCS) v = sta[i - O_STA];
    else if (i < O_SW)  v = fcst[i - O_FCS];
    else if (i < O_FW)  v = sW[i - O_SW];
    else if (i < O_UW)  v = fW[i - O_FW];
    else if (i < O_G0W) v = uW[i - O_UW];
    else if (i < O_G1W) v = g0W[i - O_G0W];
    else                v = g1W[i - O_G1W];
    dst[i] = f2b(v);
}

// ---------------------------------------------------------------------------
// Graph prep, single block of 1024: degree + wsum (LDS atomics), scan,
// CSR fill, self-loop edge attr, se = sum(We*a_edge) per (hop,head).
// ---------------------------------------------------------------------------
__global__ __launch_bounds__(1024) void prep_kernel(
    const int* __restrict__ ei, const float* __restrict__ ew,
    const float* __restrict__ We0, const float* __restrict__ ae0,
    const float* __restrict__ We1, const float* __restrict__ ae1,
    int* __restrict__ deg0, int* __restrict__ offs, float* __restrict__ loopea,
    int* __restrict__ eidx, float* __restrict__ se) {
    __shared__ int degL[1024];
    __shared__ float wsL[1024];
    __shared__ int sc[1024];
    __shared__ float seL[8];
    const int t = threadIdx.x;
    degL[t] = 0; wsL[t] = 0.f;
    if (t < 8) seL[t] = 0.f;
    __syncthreads();
    for (int e = t; e < EE; e += 1024) {
        const int d = ei[EE + e];
        atomicAdd(&degL[d], 1);
        atomicAdd(&wsL[d], ew[e]);
    }
    __syncthreads();
    const int d = degL[t];
    sc[t] = d;
    __syncthreads();
    for (int o = 1; o < 1024; o <<= 1) {
        const int v = (t >= o) ? sc[t - o] : 0;
        __syncthreads();
        sc[t] += v;
        __syncthreads();
    }
    const int excl = sc[t] - d;
    offs[t] = excl;
    deg0[t] = d;
    loopea[t] = wsL[t] / fmaxf((float)d, 1.f);
    degL[t] = excl;           // reuse as cursor
    __syncthreads();
    for (int e = t; e < EE; e += 1024) {
        const int dd = ei[EE + e];
        const int slot = atomicAdd(&degL[dd], 1);
        eidx[slot] = e;
    }
    // se: 8 groups (hop*4+head) x 128 elems
    const int g = t >> 7, k = t & 127;
    const int head = g & 3;
    const float* W = (g >> 2) ? We1 : We0;
    const float* A = (g >> 2) ? ae1 : ae0;
    atomicAdd(&seL[g], W[head * 128 + k] * A[head * 128 + k]);
    __syncthreads();
    if (t < 8) se[t] = seL[t];
}

// ---------------------------------------------------------------------------
// LSTM: 16 nodes/block, 512 blocks, 4 waves, double-buffered LDS ->
// ONE barrier per step. Merged-rcp gate math (8 transcendentals/group).
// ---------------------------------------------------------------------------
__global__ __launch_bounds__(256, 2) void lstm_kernel(
    const float* __restrict__ dyn,    // (B,T,N,16) f32
    const ushort* __restrict__ Wih,   // (512,16) bf16
    const ushort* __restrict__ Whh,   // (512,128) bf16
    const float* __restrict__ bih,
    const float* __restrict__ bhh,
    ushort* __restrict__ zsf)         // (8192,384) bf16, cols 0..127
{
    constexpr int HS = 168;           // [h(128) | x(16) | zero-pad(24)]
    __shared__ ushort hbuf[2][16 * HS];

    const int tid = threadIdx.x;
    const int blk = blockIdx.x;
    const int b = blk >> 6;
    const int n0 = (blk & 63) << 4;
    const int w = tid >> 6, lane = tid & 63, quad = lane >> 4, m = lane & 15;

    short8 Bf[5][4][2];
    float ci[2], cf[2], cg[2], co[2];
#pragma unroll
    for (int jj = 0; jj < 2; jj++) {
        const int u = (2 * w + jj) * 16 + m;
#pragma unroll
        for (int g = 0; g < 4; g++) {
            const int grow = g * 128 + u;
#pragma unroll
            for (int kt = 0; kt < 4; kt++)
                Bf[kt][g][jj] = *(const short8*)(Whh + grow * 128 + kt * 32 + quad * 8);
            if (quad < 2) Bf[4][g][jj] = *(const short8*)(Wih + grow * 16 + quad * 8);
            else          Bf[4][g][jj] = short8{0, 0, 0, 0, 0, 0, 0, 0};
        }
        ci[jj] = -L2E * (bih[u] + bhh[u]);
        cf[jj] = -L2E * (bih[128 + u] + bhh[128 + u]);
        cg[jj] =  T2E * (bih[256 + u] + bhh[256 + u]);
        co[jj] = -L2E * (bih[384 + u] + bhh[384 + u]);
    }

    float c[2][4];
#pragma unroll
    for (int jj = 0; jj < 2; jj++)
#pragma unroll
        for (int r = 0; r < 4; r++) c[jj][r] = 0.f;

    for (int i = tid; i < 2 * 16 * HS; i += 256) ((ushort*)hbuf)[i] = 0;
    __syncthreads();

    const int xn = tid >> 4, xf = tid & 15;
    const size_t xbase = (size_t)b * TT * NN * FD_ + (size_t)(n0 + xn) * FD_ + xf;
    hbuf[0][xn * HS + 128 + xf] = f2b(dyn[xbase]);         // x(0)
    float xv = dyn[xbase + (size_t)NN * FD_];              // x(1)
    __syncthreads();

    for (int t = 0; t < TT; t++) {
        const ushort* rb = hbuf[t & 1];
        ushort* wb = hbuf[(t + 1) & 1];
        if (t + 1 < TT) wb[xn * HS + 128 + xf] = f2b(xv);  // x(t+1) -> write buf
        if (t + 2 < TT) xv = dyn[xbase + (size_t)(t + 2) * NN * FD_];

        f32x4 acc[4][2];
#pragma unroll
        for (int g = 0; g < 4; g++)
#pragma unroll
            for (int jj = 0; jj < 2; jj++) acc[g][jj] = f32x4{0.f, 0.f, 0.f, 0.f};
#pragma unroll
        for (int kt = 0; kt < 5; kt++) {
            short8 a = *(const short8*)&rb[m * HS + kt * 32 + quad * 8];
#pragma unroll
            for (int g = 0; g < 4; g++)
#pragma unroll
                for (int jj = 0; jj < 2; jj++)
                    acc[g][jj] = mfma16(a, Bf[kt][g][jj], acc[g][jj]);
        }

#pragma unroll
        for (int jj = 0; jj < 2; jj++) {
            const int u = (2 * w + jj) * 16 + m;
#pragma unroll
            for (int r = 0; r < 4; r++) {
                const int n = quad * 4 + r;
                const float Di = 1.f + EXP2(fmaf(acc[0][jj][r], -L2E, ci[jj]));
                const float Df = 1.f + EXP2(fmaf(acc[1][jj][r], -L2E, cf[jj]));
                const float Eg = EXP2(fmaf(acc[2][jj][r], T2E, cg[jj]));
                const float Do = 1.f + EXP2(fmaf(acc[3][jj][r], -L2E, co[jj]));
                const float R  = RCPF(Di * (1.f + Eg));
                const float sf = RCPF(Df);
                const float cc = fmaf(sf, c[jj][r], (Eg - 1.f) * R);
                c[jj][r] = cc;
                const float Ec = EXP2(T2E * cc);
                const float h = (Ec - 1.f) * RCPF(Do * (1.f + Ec));
                wb[n * HS + u] = f2b_fast(h);
                if (t == TT - 1) zsf[(size_t)(blk * 16 + n) * 384 + u] = f2b_fast(h);
            }
        }
        __syncthreads();
    }
}

// ---------------------------------------------------------------------------
// Merged s/f GEMM: waves 0..4095 -> s = relu(sta@sW^T+sb) (K=32, cols 128..255),
// waves 4096..8191 -> f = relu(fcst@fW^T+fb) (K=8, cols 256..383).
// ---------------------------------------------------------------------------
__global__ __launch_bounds__(256) void gemm_sf_kernel(
    const ushort* __restrict__ staB, const ushort* __restrict__ sWB,
    const float* __restrict__ sb,
    const ushort* __restrict__ fcsB, const ushort* __restrict__ fWB,
    const float* __restrict__ fb, ushort* __restrict__ zsf) {
    const int tid = threadIdx.x;
    const int lane = tid & 63, quad = lane >> 4, m = lane & 15;
    int wave = blockIdx.x * 4 + (tid >> 6);
    const short8 z8 = short8{0, 0, 0, 0, 0, 0, 0, 0};
    short8 a, bf;
    int r0, c0, ocol;
    const float* bias;
    if (wave < 4096) {
        r0 = (wave >> 3) * 16; c0 = (wave & 7) * 16; ocol = 128; bias = sb;
        a  = *(const short8*)(staB + (size_t)(r0 + m) * 32 + quad * 8);
        bf = *(const short8*)(sWB + (size_t)(c0 + m) * 32 + quad * 8);
    } else {
        wave -= 4096;
        r0 = (wave >> 3) * 16; c0 = (wave & 7) * 16; ocol = 256; bias = fb;
        a  = (quad == 0) ? *(const short8*)(fcsB + (size_t)(r0 + m) * 8) : z8;
        bf = (quad == 0) ? *(const short8*)(fWB + (size_t)(c0 + m) * 8) : z8;
    }
    f32x4 acc = mfma16(a, bf, f32x4{0.f, 0.f, 0.f, 0.f});
    const float bv = bias[c0 + m];
#pragma unroll
    for (int r = 0; r < 4; r++) {
        const int row = r0 + quad * 4 + r;
        zsf[(size_t)row * 384 + ocol + c0 + m] = f2b(fmaxf(acc[r] + bv, 0.f));
    }
}

// ---------------------------------------------------------------------------
// Fusion GEMM: h = relu(zsf @ uW^T + ub), K=384; writes hB (bf16) + hF (f32).
// ---------------------------------------------------------------------------
__global__ __launch_bounds__(256) void gemm_fusion_kernel(
    const ushort* __restrict__ A, const ushort* __restrict__ Bt,
    const float* __restrict__ bias, ushort* __restrict__ hB, float* __restrict__ hF) {
    const int tid = threadIdx.x;
    const int lane = tid & 63, quad = lane >> 4, m = lane & 15;
    const int wave = blockIdx.x * 4 + (tid >> 6);
    const int r0 = (wave >> 3) * 16, c0 = (wave & 7) * 16;
    f32x4 acc = f32x4{0.f, 0.f, 0.f, 0.f};
#pragma unroll
    for (int kt = 0; kt < 12; kt++) {
        const int k = kt * 32 + quad * 8;
        short8 a  = *(const short8*)(A + (size_t)(r0 + m) * 384 + k);
        short8 bf = *(const short8*)(Bt + (size_t)(c0 + m) * 384 + k);
        acc = mfma16(a, bf, acc);
    }
    const int col = c0 + m;
    const float bv = bias[col];
#pragma unroll
    for (int r = 0; r < 4; r++) {
        const int row = r0 + quad * 4 + r;
        const float v = fmaxf(acc[r] + bv, 0.f);
        hB[(size_t)row * 128 + col] = f2b(v);
        hF[(size_t)row * 128 + col] = v;
    }
}

// ---------------------------------------------------------------------------
// Hop GEMM + fused attention scalars. Block = 16 rows; wave w = head w
// (cols w*128..w*128+127). Epilogue: as_/ad_ dot in-register + 16-lane reduce.
// ---------------------------------------------------------------------------
__global__ __launch_bounds__(256) void gemmatt_kernel(
    const ushort* __restrict__ hB, const ushort* __restrict__ W,
    const float* __restrict__ asrc, const float* __restrict__ adst,
    ushort* __restrict__ xl, float* __restrict__ as_, float* __restrict__ ad_) {
    const int tid = threadIdx.x;
    const int lane = tid & 63, quad = lane >> 4, m = lane & 15;
    const int w = tid >> 6;
    const int r0 = blockIdx.x * 16;
    f32x4 acc[8];
#pragma unroll
    for (int ct = 0; ct < 8; ct++) acc[ct] = f32x4{0.f, 0.f, 0.f, 0.f};
#pragma unroll
    for (int kt = 0; kt < 4; kt++) {
        const int k = kt * 32 + quad * 8;
        short8 a = *(const short8*)(hB + (size_t)(r0 + m) * 128 + k);
#pragma unroll
        for (int ct = 0; ct < 8; ct++) {
            short8 bf = *(const short8*)(W + (size_t)(w * 128 + ct * 16 + m) * 128 + k);
            acc[ct] = mfma16(a, bf, acc[ct]);
        }
    }
    float sa[4] = {0.f, 0.f, 0.f, 0.f}, sd[4] = {0.f, 0.f, 0.f, 0.f};
#pragma unroll
    for (int ct = 0; ct < 8; ct++) {
        const int col = w * 128 + ct * 16 + m;
        const float av = asrc[col], dv = adst[col];
#pragma unroll
        for (int r = 0; r < 4; r++) {
            const float v = acc[ct][r];
            xl[(size_t)(r0 + quad * 4 + r) * 512 + col] = f2b(v);
            sa[r] = fmaf(v, av, sa[r]);
            sd[r] = fmaf(v, dv, sd[r]);
        }
    }
#pragma unroll
    for (int o = 1; o < 16; o <<= 1) {
#pragma unroll
        for (int r = 0; r < 4; r++) {
            sa[r] += __shfl_xor(sa[r], o);
            sd[r] += __shfl_xor(sd[r], o);
        }
    }
    if (m == 0) {
#pragma unroll
        for (int r = 0; r < 4; r++) {
            const int node = r0 + quad * 4 + r;
            as_[node * 4 + w] = sa[r];
            ad_[node * 4 + w] = sd[r];
        }
    }
}

// ---------------------------------------------------------------------------
// Per-(batch,edge,head) unnormalized softmax weight: exp(leaky(logit)).
// ---------------------------------------------------------------------------
__global__ __launch_bounds__(256) void edge_exp_kernel(
    const int* __restrict__ ei, const float* __restrict__ ew,
    const float* __restrict__ as_, const float* __restrict__ ad_,
    const float* __restrict__ se4, float* __restrict__ pexp) {
    const int idx = blockIdx.x * 256 + threadIdx.x;   // 131072
    const int b = idx >> 14, e = idx & (EE - 1);
    const int src = b * 1024 + ei[e];
    const int dst = b * 1024 + ei[EE + e];
    const float eaw = ew[e];
    const float4 s4 = *(const float4*)(as_ + src * 4);
    const float4 d4 = *(const float4*)(ad_ + dst * 4);
    float4 p;
    float* pp = (float*)&p;
    const float* s = (const float*)&s4;
    const float* d = (const float*)&d4;
#pragma unroll
    for (int h = 0; h < 4; h++) {
        float a = s[h] + d[h] + eaw * se4[h];
        a = (a < 0.f) ? 0.2f * a : a;
        pp[h] = EXP2(fminf(a, 60.f) * L2E);
    }
    *(float4*)(pexp + (size_t)idx * 4) = p;
}

// ---------------------------------------------------------------------------
// Fused GAT hop, SINGLE pass: wave per (dst,batch); per-head numerator +
// denominator accumulated together, normalize at end; bias/relu/residual/LN.
// Hop1 (writeOut): skip hF/hB writeback, emit final projection instead.
// ---------------------------------------------------------------------------
__global__ __launch_bounds__(256) void gat_kernel(
    float* __restrict__ hF, ushort* __restrict__ hB, const ushort* __restrict__ xl,
    const float* __restrict__ as_, const float* __restrict__ ad_,
    const float* __restrict__ pexp,
    const int* __restrict__ eidx, const int* __restrict__ offs,
    const int* __restrict__ deg0, const float* __restrict__ loopea,
    const int* __restrict__ ei,
    const float* __restrict__ se4, const float* __restrict__ bias,
    const float* __restrict__ lng, const float* __restrict__ lnb, int relu,
    int writeOut, const float* __restrict__ oW, const float* __restrict__ ob,
    float* __restrict__ out) {
    const int lane = threadIdx.x & 63;
    const int v = blockIdx.x * 4 + (threadIdx.x >> 6);
    const int b = v >> 10, n = v & 1023;
    const int dg = deg0[n], off = offs[n];

    // self loop
    const float lea = loopea[n];
    const float4 s4 = *(const float4*)(as_ + v * 4);
    const float4 d4 = *(const float4*)(ad_ + v * 4);
    const float* sp = (const float*)&s4;
    const float* dp = (const float*)&d4;
    float den[4], num0[4], num1[4];
#pragma unroll
    for (int h = 0; h < 4; h++) {
        float a = sp[h] + dp[h] + lea * se4[h];
        a = (a < 0.f) ? 0.2f * a : a;
        const float p = EXP2(fminf(a, 60.f) * L2E);
        den[h] = p;
        num0[h] = p * b2f(xl[(size_t)v * 512 + h * 128 + lane]);
        num1[h] = p * b2f(xl[(size_t)v * 512 + h * 128 + 64 + lane]);
    }
    for (int i = 0; i < dg; i++) {
        const int e = eidx[off + i];
        const int src = b * 1024 + ei[e];
        const float4 p4 = *(const float4*)(pexp + (size_t)(b * EE + e) * 4);
        const float* p = (const float*)&p4;
        const ushort* xr = xl + (size_t)src * 512;
#pragma unroll
        for (int h = 0; h < 4; h++) {
            den[h] += p[h];
            num0[h] = fmaf(p[h], b2f(xr[h * 128 + lane]), num0[h]);
            num1[h] = fmaf(p[h], b2f(xr[h * 128 + 64 + lane]), num1[h]);
        }
    }
    float o0 = 0.f, o1 = 0.f;
#pragma unroll
    for (int h = 0; h < 4; h++) {
        const float inv = RCPF(den[h]);
        o0 = fmaf(num0[h], inv, o0);
        o1 = fmaf(num1[h], inv, o1);
    }

    float d0 = o0 * 0.25f + bias[lane];
    float d1 = o1 * 0.25f + bias[64 + lane];
    if (relu) { d0 = fmaxf(d0, 0.f); d1 = fmaxf(d1, 0.f); }
    const float x0 = hF[(size_t)v * 128 + lane] + d0;
    const float x1 = hF[(size_t)v * 128 + 64 + lane] + d1;

    float s = x0 + x1;
#pragma unroll
    for (int o = 32; o; o >>= 1) s += __shfl_xor(s, o);
    const float mu = s * (1.f / 128.f);
    const float e0 = x0 - mu, e1 = x1 - mu;
    float vs = e0 * e0 + e1 * e1;
#pragma unroll
    for (int o = 32; o; o >>= 1) vs += __shfl_xor(vs, o);
    const float r = rsqrtf(vs * (1.f / 128.f) + 1e-5f);
    const float y0 = e0 * r * lng[lane] + lnb[lane];
    const float y1 = e1 * r * lng[64 + lane] + lnb[64 + lane];
    if (writeOut) {
        float t = y0 * oW[lane] + y1 * oW[64 + lane];
#pragma unroll
        for (int o = 32; o; o >>= 1) t += __shfl_xor(t, o);
        if (lane == 0) out[v] = t + ob[0];
    } else {
        hF[(size_t)v * 128 + lane] = y0;
        hF[(size_t)v * 128 + 64 + lane] = y1;
        hB[(size_t)v * 128 + lane] = f2b(y0);
        hB[(size_t)v * 128 + 64 + lane] = f2b(y1);
    }
}

// ---------------------------------------------------------------------------
extern "C" void kernel_launch(void* const* d_in, const int* in_sizes, int n_in,
                              void* d_out, int out_size, void* d_ws, size_t ws_size,
                              hipStream_t stream) {
    const float* dyn  = (const float*)d_in[0];
    const float* fcst = (const float*)d_in[1];
    const float* sta  = (const float*)d_in[2];
    const int*   ei   = (const int*)d_in[3];
    const float* ew   = (const float*)d_in[4];
    const float* lWih = (const float*)d_in[5];
    const float* lWhh = (const float*)d_in[6];
    const float* lbih = (const float*)d_in[7];
    const float* lbhh = (const float*)d_in[8];
    const float* sW = (const float*)d_in[9];
    const float* sb = (const float*)d_in[10];
    const float* fW = (const float*)d_in[11];
    const float* fb = (const float*)d_in[12];
    const float* uW = (const float*)d_in[13];
    const float* ub = (const float*)d_in[14];
    const float* g0W  = (const float*)d_in[15];
    const float* g0as = (const float*)d_in[16];
    const float* g0ad = (const float*)d_in[17];
    const float* g0ae = (const float*)d_in[18];
    const float* g0We = (const float*)d_in[19];
    const float* g0b  = (const float*)d_in[20];
    const float* g1W  = (const float*)d_in[21];
    const float* g1as = (const float*)d_in[22];
    const float* g1ad = (const float*)d_in[23];
    const float* g1ae = (const float*)d_in[24];
    const float* g1We = (const float*)d_in[25];
    const float* g1b  = (const float*)d_in[26];
    const float* ln0g = (const float*)d_in[27];
    const float* ln0b = (const float*)d_in[28];
    const float* ln1g = (const float*)d_in[29];
    const float* ln1b = (const float*)d_in[30];
    const float* oW = (const float*)d_in[31];
    const float* ob = (const float*)d_in[32];

    char* p = (char*)d_ws;
    ushort* castB = (ushort*)p; p += (size_t)O_END * 2 + 512;
    ushort* zsf = (ushort*)p;  p += (size_t)BN_ * 384 * 2;      // pexp overlays (dead after fusion)
    float*  hF  = (float*)p;   p += (size_t)BN_ * 128 * 4;
    ushort* hB  = (ushort*)p;  p += (size_t)BN_ * 128 * 2;
    ushort* xl  = (ushort*)p;  p += (size_t)BN_ * 512 * 2;
    float*  asb = (float*)p;   p += (size_t)BN_ * 4 * 4;
    float*  adb = (float*)p;   p += (size_t)BN_ * 4 * 4;
    int*    deg0   = (int*)p;   p += 4096;
    int*    offs   = (int*)p;   p += 4096;
    float*  loopea = (float*)p; p += 4096;
    int*    eidx   = (int*)p;   p += (size_t)EE * 4;
    float*  se     = (float*)p; p += 256;
    float*  pexp   = (float*)zsf;   // 8*16384*4 f32 = 2 MB < 6.3 MB

    const ushort* WihB = castB + O_WIH;
    const ushort* WhhB = castB + O_WHH;
    const ushort* staB = castB + O_STA;
    const ushort* fcsB = castB + O_FCS;
    const ushort* sWB  = castB + O_SW;
    const ushort* fWB  = castB + O_FW;
    const ushort* uWB  = castB + O_UW;
    const ushort* g0WB = castB + O_G0W;
    const ushort* g1WB = castB + O_G1W;

    cast_kernel<<<(O_END + 255) / 256, 256, 0, stream>>>(lWih, lWhh, sta, fcst, sW, fW,
                                                         uW, g0W, g1W, castB);
    prep_kernel<<<1, 1024, 0, stream>>>(ei, ew, g0We, g0ae, g1We, g1ae,
                                        deg0, offs, loopea, eidx, se);

    lstm_kernel<<<512, 256, 0, stream>>>(dyn, WihB, WhhB, lbih, lbhh, zsf);
    gemm_sf_kernel<<<2048, 256, 0, stream>>>(staB, sWB, sb, fcsB, fWB, fb, zsf);
    gemm_fusion_kernel<<<1024, 256, 0, stream>>>(zsf, uWB, ub, hB, hF);

    // hop 0
    gemmatt_kernel<<<512, 256, 0, stream>>>(hB, g0WB, g0as, g0ad, xl, asb, adb);
    edge_exp_kernel<<<512, 256, 0, stream>>>(ei, ew, asb, adb, se, pexp);
    gat_kernel<<<2048, 256, 0, stream>>>(hF, hB, xl, asb, adb, pexp, eidx, offs, deg0,
                                         loopea, ei, se, g0b, ln0g, ln0b, 1,
                                         0, oW, ob, (float*)d_out);
    // hop 1
    gemmatt_kernel<<<512, 256, 0, stream>>>(hB, g1WB, g1as, g1ad, xl, asb, adb);
    edge_exp_kernel<<<512, 256, 0, stream>>>(ei, ew, asb, adb, se + 4, pexp);
    gat_kernel<<<2048, 256, 0, stream>>>(hF, hB, xl, asb, adb, pexp, eidx, offs, deg0,
                                         loopea, ei, se + 4, g1b, ln1g, ln1b, 0,
                                         1, oW, ob, (float*)d_out);
}